// Round 2
// baseline (622.371 us; speedup 1.0000x reference)
//
#include <hip/hip_runtime.h>

// VoxelEncoding via counting-sort by voxel id:
//   K0 zero hist -> K1 histogram(p2v) -> K2 block scan -> K3 scan block sums
//   -> K4 add offsets
//   -> K5 scatter ONLY the 4-B original index (ord[pos]=i): random 4-B
//      writes into an 8 MB array line-merge in L2 (the old 20-B payload
//      scatter produced 192 MB of unmerged L2-miss writes = 165 us)
//   -> K5b gather: ord seq-read -> random pts/p2v READS (L3-hot, no RMW,
//      no dirty-line eviction) -> sequential full-line rec/vsort writes.
//      Random-read+seq-write is the cheap direction for a permutation.
//   -> K6 main: identical to the proven round-0 kernel: seq vsort/rec,
//      3-deep miss chain, 1 line per point of position payload. Same-voxel
//      points adjacent -> duplicate embedding gathers merge in TA/L1;
//      c2c/cp reads near-sequential; output scattered back to orig rows
//      (64-B aligned full lines, no amplification).

typedef float v4f __attribute__((ext_vector_type(4)));

// ---------------- K0: zero histogram ----------------
__global__ void k_zero(unsigned* __restrict__ hist, int n) {
    int i = blockIdx.x * blockDim.x + threadIdx.x;
    if (i < n) hist[i] = 0u;
}

// ---------------- K1: histogram ----------------
__global__ void k_hist(const int* __restrict__ p2v, unsigned* __restrict__ hist, int N) {
    int i = blockIdx.x * blockDim.x + threadIdx.x;
    if (i < N) atomicAdd(&hist[p2v[i]], 1u);
}

// ---------------- K2: per-block exclusive scan (1024 bins/block) ----------------
__global__ __launch_bounds__(256) void k_scan_blocks(unsigned* __restrict__ hist,
                                                     unsigned* __restrict__ bsums, int nbins) {
    __shared__ unsigned tsum[256];
    const int tid = threadIdx.x;
    const int i0 = blockIdx.x * 1024 + tid * 4;
    unsigned v[4]; unsigned s = 0;
    #pragma unroll
    for (int k = 0; k < 4; ++k) {
        unsigned c = (i0 + k < nbins) ? hist[i0 + k] : 0u;
        v[k] = s; s += c;
    }
    tsum[tid] = s; __syncthreads();
    for (int off = 1; off < 256; off <<= 1) {
        unsigned x = tsum[tid];
        unsigned y = (tid >= off) ? tsum[tid - off] : 0u;
        __syncthreads();
        tsum[tid] = x + y;
        __syncthreads();
    }
    unsigned prefix = (tid > 0) ? tsum[tid - 1] : 0u;
    #pragma unroll
    for (int k = 0; k < 4; ++k) {
        if (i0 + k < nbins) hist[i0 + k] = prefix + v[k];
    }
    if (tid == 255) bsums[blockIdx.x] = tsum[255];
}

// ---------------- K3: exclusive scan of block sums (single block, nb <= 1024) ----------------
__global__ __launch_bounds__(256) void k_scan_sums(unsigned* __restrict__ bsums, int nb) {
    __shared__ unsigned tsum[256];
    const int tid = threadIdx.x;
    const int i0 = tid * 4;
    unsigned v[4]; unsigned s = 0;
    #pragma unroll
    for (int k = 0; k < 4; ++k) {
        unsigned c = (i0 + k < nb) ? bsums[i0 + k] : 0u;
        v[k] = s; s += c;
    }
    tsum[tid] = s; __syncthreads();
    for (int off = 1; off < 256; off <<= 1) {
        unsigned x = tsum[tid];
        unsigned y = (tid >= off) ? tsum[tid - off] : 0u;
        __syncthreads();
        tsum[tid] = x + y;
        __syncthreads();
    }
    unsigned prefix = (tid > 0) ? tsum[tid - 1] : 0u;
    #pragma unroll
    for (int k = 0; k < 4; ++k) {
        if (i0 + k < nb) bsums[i0 + k] = prefix + v[k];
    }
}

// ---------------- K4: add block offsets -> global exclusive offsets ----------------
__global__ void k_add(unsigned* __restrict__ hist, const unsigned* __restrict__ bsums, int nbins) {
    int i = blockIdx.x * blockDim.x + threadIdx.x;
    if (i < nbins) hist[i] += bsums[i >> 10];
}

// ---------------- K5: scatter ONLY original index to sorted order ----------------
__global__ void k_scatter(const int* __restrict__ p2v,
                          unsigned* __restrict__ hist,
                          unsigned* __restrict__ ord, int N) {
    int i = blockIdx.x * blockDim.x + threadIdx.x;
    if (i >= N) return;
    const int v = p2v[i];
    const unsigned pos = atomicAdd(&hist[v], 1u);
    ord[pos] = (unsigned)i;
}

// ---------------- K5b: gather permutation -> sequential payload ----------------
// 1 thread per sorted point. Random READS (cheap, L3-hot) -> seq full-line writes.
__global__ __launch_bounds__(256) void k_gather(
    const unsigned* __restrict__ ord,
    const float* __restrict__ pts,
    const int*   __restrict__ p2v,
    v4f*         __restrict__ rec,
    unsigned*    __restrict__ vsort,
    int N)
{
    int n = blockIdx.x * blockDim.x + threadIdx.x;
    if (n >= N) return;
    const int orig = (int)ord[n];
    v4f r;
    r.x = pts[3 * (size_t)orig + 0];
    r.y = pts[3 * (size_t)orig + 1];
    r.z = pts[3 * (size_t)orig + 2];
    r.w = __int_as_float(orig);
    rec[n] = r;
    vsort[n] = (unsigned)p2v[orig];
}

// ---------------- K6: main interpolation over sorted points ----------------
__global__ __launch_bounds__(256) void k_main(
    const unsigned* __restrict__ vsort, const v4f* __restrict__ rec,
    const float* __restrict__ emb,   // (N_EMB,16)
    const float* __restrict__ cp,    // (N_VOX,3)
    const int*   __restrict__ c2c,   // (N_VOX,8)
    const float* __restrict__ vox,
    float*       __restrict__ out,   // (N,16)
    int N)
{
    const int t = blockIdx.x * blockDim.x + threadIdx.x;
    const int n = t >> 2;        // sorted point index
    const int q = t & 3;         // 4-dim chunk
    if (n >= N) return;

    const unsigned v = vsort[n];
    const v4f r = rec[n];
    const int orig = __float_as_int(r.w);

    const int4* c4 = (const int4*)(c2c + 8 * (size_t)v);
    const int4 ci0 = c4[0];
    const int4 ci1 = c4[1];
    const int cidx[8] = {ci0.x, ci0.y, ci0.z, ci0.w, ci1.x, ci1.y, ci1.z, ci1.w};

    v4f e[8];
    #pragma unroll
    for (int c = 0; c < 8; ++c) {
        e[c] = *(const v4f*)(emb + 16 * (size_t)cidx[c] + 4 * q);
    }

    const float inv_vs = 1.0f / vox[0];
    const float* cpp = cp + 3 * (size_t)v;
    const float px = (r.x - cpp[0]) * inv_vs + 0.5f;
    const float py = (r.y - cpp[1]) * inv_vs + 0.5f;
    const float pz = (r.z - cpp[2]) * inv_vs + 0.5f;
    const float wx[2] = {1.0f - px, px};
    const float wy[2] = {1.0f - py, py};
    const float wz[2] = {1.0f - pz, pz};

    v4f acc = (v4f)(0.0f);
    #pragma unroll
    for (int c = 0; c < 8; ++c) {
        const float w = wx[(c >> 2) & 1] * wy[(c >> 1) & 1] * wz[c & 1];
        acc.x = fmaf(w, e[c].x, acc.x);
        acc.y = fmaf(w, e[c].y, acc.y);
        acc.z = fmaf(w, e[c].z, acc.z);
        acc.w = fmaf(w, e[c].w, acc.w);
    }

    __builtin_nontemporal_store(acc, (v4f*)(out + 16 * (size_t)orig + 4 * q));
}

// ---------------- fallback (no-sort direct), used only if ws too small ----------------
__global__ __launch_bounds__(256) void k_direct(
    const float* __restrict__ pts, const int* __restrict__ p2v,
    const float* __restrict__ emb, const float* __restrict__ cp,
    const int* __restrict__ c2c, const float* __restrict__ vox,
    float* __restrict__ out, int N)
{
    const int t = blockIdx.x * blockDim.x + threadIdx.x;
    const int n = t >> 2, q = t & 3;
    if (n >= N) return;
    const int v = p2v[n];
    const int4* c4 = (const int4*)(c2c + 8 * (size_t)v);
    const int4 ci0 = c4[0], ci1 = c4[1];
    const int cidx[8] = {ci0.x, ci0.y, ci0.z, ci0.w, ci1.x, ci1.y, ci1.z, ci1.w};
    v4f e[8];
    #pragma unroll
    for (int c = 0; c < 8; ++c) e[c] = *(const v4f*)(emb + 16 * (size_t)cidx[c] + 4 * q);
    const float inv_vs = 1.0f / vox[0];
    const float* pp = pts + 3 * (size_t)n;
    const float* cpp = cp + 3 * (size_t)v;
    const float px = (pp[0] - cpp[0]) * inv_vs + 0.5f;
    const float py = (pp[1] - cpp[1]) * inv_vs + 0.5f;
    const float pz = (pp[2] - cpp[2]) * inv_vs + 0.5f;
    const float wx[2] = {1.0f - px, px};
    const float wy[2] = {1.0f - py, py};
    const float wz[2] = {1.0f - pz, pz};
    v4f acc = (v4f)(0.0f);
    #pragma unroll
    for (int c = 0; c < 8; ++c) {
        const float w = wx[(c >> 2) & 1] * wy[(c >> 1) & 1] * wz[c & 1];
        acc.x = fmaf(w, e[c].x, acc.x); acc.y = fmaf(w, e[c].y, acc.y);
        acc.z = fmaf(w, e[c].z, acc.z); acc.w = fmaf(w, e[c].w, acc.w);
    }
    __builtin_nontemporal_store(acc, (v4f*)(out + 4 * (size_t)t));
}

extern "C" void kernel_launch(void* const* d_in, const int* in_sizes, int n_in,
                              void* d_out, int out_size, void* d_ws, size_t ws_size,
                              hipStream_t stream) {
    const float* pts = (const float*)d_in[0];
    const int*   p2v = (const int*)d_in[1];
    const float* emb = (const float*)d_in[2];
    const float* cp  = (const float*)d_in[3];
    const int*   c2c = (const int*)d_in[4];
    const float* vox = (const float*)d_in[5];
    float*       out = (float*)d_out;

    const int N  = in_sizes[1];       // 2,000,000 points
    const int NV = in_sizes[4] / 8;   // 500,000 voxels

    // workspace layout (bytes)
    const size_t off_hist  = 0;                        // NV * 4   (2 MB)
    const size_t off_bsums = 2u * 1024u * 1024u;       // <=1024 * 4
    const size_t off_ord   = 4u * 1024u * 1024u;       // N * 4    (8 MB)
    const size_t off_vsort = 12u * 1024u * 1024u;      // N * 4    (8 MB)
    const size_t off_rec   = 20u * 1024u * 1024u;      // N * 16   (32 MB)
    const size_t need = off_rec + (size_t)N * 16u;

    if (ws_size < need) {
        const int block = 256;
        const long long threads = 4LL * N;
        k_direct<<<(int)((threads + block - 1) / block), block, 0, stream>>>(
            pts, p2v, emb, cp, c2c, vox, out, N);
        return;
    }

    unsigned* hist  = (unsigned*)((char*)d_ws + off_hist);
    unsigned* bsums = (unsigned*)((char*)d_ws + off_bsums);
    unsigned* ord   = (unsigned*)((char*)d_ws + off_ord);
    unsigned* vsort = (unsigned*)((char*)d_ws + off_vsort);
    v4f*      rec   = (v4f*)((char*)d_ws + off_rec);

    const int block = 256;
    const int nscan = (NV + 1023) / 1024;   // 489 blocks; k_scan_sums handles <=1024

    k_zero<<<(NV + block - 1) / block, block, 0, stream>>>(hist, NV);
    k_hist<<<(N + block - 1) / block, block, 0, stream>>>(p2v, hist, N);
    k_scan_blocks<<<nscan, 256, 0, stream>>>(hist, bsums, NV);
    k_scan_sums<<<1, 256, 0, stream>>>(bsums, nscan);
    k_add<<<(NV + block - 1) / block, block, 0, stream>>>(hist, bsums, NV);
    k_scatter<<<(N + block - 1) / block, block, 0, stream>>>(p2v, hist, ord, N);
    k_gather<<<(N + block - 1) / block, block, 0, stream>>>(ord, pts, p2v, rec, vsort, N);

    const long long threads = 4LL * N;
    k_main<<<(int)((threads + block - 1) / block), block, 0, stream>>>(
        vsort, rec, emb, cp, c2c, vox, out, N);
}

// Round 3
// 478.033 us; speedup vs baseline: 1.3019x; 1.3019x over previous
//
#include <hip/hip_runtime.h>

// VoxelEncoding via counting-sort by voxel id — single-atomic-pass version.
//   Measured (r0-r2): each 2M device-scope atomicAdd pass costs ~130-175 us
//   (far-atomic op-rate bound: WRITE_SIZE carries a constant ~128 MB = 2M x
//   64-B partial-line RMW at the coherence point; BW only 10% of peak,
//   VALUBusy 0.25%). The old pipeline paid this TWICE (k_hist + k_scatter).
//   Now: the histogram's atomicAdd RETURN VALUE is the point's rank within
//   its voxel -> record it; after the scan, pos = offset[v] + rank[i] is a
//   pure load -> k_place scatters payload with ZERO atomics.
//
//   K0 zero hist -> K1 hist+rank (the only atomic pass)
//   -> K2 block scan -> K3 scan block sums -> K4 add offsets
//   -> K5 place: pos = hist[v]+rank[i]; write vsort/rec scattered
//      (40 MB payload, ~1.65x write amplification measured in r0)
//   -> K6 main (unchanged, proven): seq vsort/rec reads; same-voxel points
//      adjacent -> duplicate embedding gathers merge in TA/L1; c2c/cp reads
//      near-sequential; output scattered to orig rows (full 64-B lines).

typedef float v4f __attribute__((ext_vector_type(4)));

// ---------------- K0: zero histogram ----------------
__global__ void k_zero(unsigned* __restrict__ hist, int n) {
    int i = blockIdx.x * blockDim.x + threadIdx.x;
    if (i < n) hist[i] = 0u;
}

// ---------------- K1: histogram + per-point rank (single atomic pass) ----------------
__global__ void k_hist_rank(const int* __restrict__ p2v,
                            unsigned* __restrict__ hist,
                            unsigned* __restrict__ rank, int N) {
    int i = blockIdx.x * blockDim.x + threadIdx.x;
    if (i < N) rank[i] = atomicAdd(&hist[p2v[i]], 1u);
}

// ---------------- K2: per-block exclusive scan (1024 bins/block) ----------------
__global__ __launch_bounds__(256) void k_scan_blocks(unsigned* __restrict__ hist,
                                                     unsigned* __restrict__ bsums, int nbins) {
    __shared__ unsigned tsum[256];
    const int tid = threadIdx.x;
    const int i0 = blockIdx.x * 1024 + tid * 4;
    unsigned v[4]; unsigned s = 0;
    #pragma unroll
    for (int k = 0; k < 4; ++k) {
        unsigned c = (i0 + k < nbins) ? hist[i0 + k] : 0u;
        v[k] = s; s += c;
    }
    tsum[tid] = s; __syncthreads();
    for (int off = 1; off < 256; off <<= 1) {
        unsigned x = tsum[tid];
        unsigned y = (tid >= off) ? tsum[tid - off] : 0u;
        __syncthreads();
        tsum[tid] = x + y;
        __syncthreads();
    }
    unsigned prefix = (tid > 0) ? tsum[tid - 1] : 0u;
    #pragma unroll
    for (int k = 0; k < 4; ++k) {
        if (i0 + k < nbins) hist[i0 + k] = prefix + v[k];
    }
    if (tid == 255) bsums[blockIdx.x] = tsum[255];
}

// ---------------- K3: exclusive scan of block sums (single block, nb <= 1024) ----------------
__global__ __launch_bounds__(256) void k_scan_sums(unsigned* __restrict__ bsums, int nb) {
    __shared__ unsigned tsum[256];
    const int tid = threadIdx.x;
    const int i0 = tid * 4;
    unsigned v[4]; unsigned s = 0;
    #pragma unroll
    for (int k = 0; k < 4; ++k) {
        unsigned c = (i0 + k < nb) ? bsums[i0 + k] : 0u;
        v[k] = s; s += c;
    }
    tsum[tid] = s; __syncthreads();
    for (int off = 1; off < 256; off <<= 1) {
        unsigned x = tsum[tid];
        unsigned y = (tid >= off) ? tsum[tid - off] : 0u;
        __syncthreads();
        tsum[tid] = x + y;
        __syncthreads();
    }
    unsigned prefix = (tid > 0) ? tsum[tid - 1] : 0u;
    #pragma unroll
    for (int k = 0; k < 4; ++k) {
        if (i0 + k < nb) bsums[i0 + k] = prefix + v[k];
    }
}

// ---------------- K4: add block offsets -> global exclusive offsets ----------------
__global__ void k_add(unsigned* __restrict__ hist, const unsigned* __restrict__ bsums, int nbins) {
    int i = blockIdx.x * blockDim.x + threadIdx.x;
    if (i < nbins) hist[i] += bsums[i >> 10];
}

// ---------------- K5: place payload at pos = offset[v] + rank[i] (NO atomics) ----------------
__global__ __launch_bounds__(256) void k_place(
    const float* __restrict__ pts,
    const int*   __restrict__ p2v,
    const unsigned* __restrict__ rank,
    const unsigned* __restrict__ hist,   // exclusive offsets after scan
    unsigned* __restrict__ vsort,
    v4f*      __restrict__ rec,
    int N)
{
    int i = blockIdx.x * blockDim.x + threadIdx.x;
    if (i >= N) return;
    const int v = p2v[i];
    const unsigned pos = hist[v] + rank[i];
    vsort[pos] = (unsigned)v;
    v4f r;
    r.x = pts[3 * (size_t)i + 0];
    r.y = pts[3 * (size_t)i + 1];
    r.z = pts[3 * (size_t)i + 2];
    r.w = __int_as_float(i);
    rec[pos] = r;
}

// ---------------- K6: main interpolation over sorted points ----------------
__global__ __launch_bounds__(256) void k_main(
    const unsigned* __restrict__ vsort, const v4f* __restrict__ rec,
    const float* __restrict__ emb,   // (N_EMB,16)
    const float* __restrict__ cp,    // (N_VOX,3)
    const int*   __restrict__ c2c,   // (N_VOX,8)
    const float* __restrict__ vox,
    float*       __restrict__ out,   // (N,16)
    int N)
{
    const int t = blockIdx.x * blockDim.x + threadIdx.x;
    const int n = t >> 2;        // sorted point index
    const int q = t & 3;         // 4-dim chunk
    if (n >= N) return;

    const unsigned v = vsort[n];
    const v4f r = rec[n];
    const int orig = __float_as_int(r.w);

    const int4* c4 = (const int4*)(c2c + 8 * (size_t)v);
    const int4 ci0 = c4[0];
    const int4 ci1 = c4[1];
    const int cidx[8] = {ci0.x, ci0.y, ci0.z, ci0.w, ci1.x, ci1.y, ci1.z, ci1.w};

    v4f e[8];
    #pragma unroll
    for (int c = 0; c < 8; ++c) {
        e[c] = *(const v4f*)(emb + 16 * (size_t)cidx[c] + 4 * q);
    }

    const float inv_vs = 1.0f / vox[0];
    const float* cpp = cp + 3 * (size_t)v;
    const float px = (r.x - cpp[0]) * inv_vs + 0.5f;
    const float py = (r.y - cpp[1]) * inv_vs + 0.5f;
    const float pz = (r.z - cpp[2]) * inv_vs + 0.5f;
    const float wx[2] = {1.0f - px, px};
    const float wy[2] = {1.0f - py, py};
    const float wz[2] = {1.0f - pz, pz};

    v4f acc = (v4f)(0.0f);
    #pragma unroll
    for (int c = 0; c < 8; ++c) {
        const float w = wx[(c >> 2) & 1] * wy[(c >> 1) & 1] * wz[c & 1];
        acc.x = fmaf(w, e[c].x, acc.x);
        acc.y = fmaf(w, e[c].y, acc.y);
        acc.z = fmaf(w, e[c].z, acc.z);
        acc.w = fmaf(w, e[c].w, acc.w);
    }

    __builtin_nontemporal_store(acc, (v4f*)(out + 16 * (size_t)orig + 4 * q));
}

// ---------------- fallback (no-sort direct), used only if ws too small ----------------
__global__ __launch_bounds__(256) void k_direct(
    const float* __restrict__ pts, const int* __restrict__ p2v,
    const float* __restrict__ emb, const float* __restrict__ cp,
    const int* __restrict__ c2c, const float* __restrict__ vox,
    float* __restrict__ out, int N)
{
    const int t = blockIdx.x * blockDim.x + threadIdx.x;
    const int n = t >> 2, q = t & 3;
    if (n >= N) return;
    const int v = p2v[n];
    const int4* c4 = (const int4*)(c2c + 8 * (size_t)v);
    const int4 ci0 = c4[0], ci1 = c4[1];
    const int cidx[8] = {ci0.x, ci0.y, ci0.z, ci0.w, ci1.x, ci1.y, ci1.z, ci1.w};
    v4f e[8];
    #pragma unroll
    for (int c = 0; c < 8; ++c) e[c] = *(const v4f*)(emb + 16 * (size_t)cidx[c] + 4 * q);
    const float inv_vs = 1.0f / vox[0];
    const float* pp = pts + 3 * (size_t)n;
    const float* cpp = cp + 3 * (size_t)v;
    const float px = (pp[0] - cpp[0]) * inv_vs + 0.5f;
    const float py = (pp[1] - cpp[1]) * inv_vs + 0.5f;
    const float pz = (pp[2] - cpp[2]) * inv_vs + 0.5f;
    const float wx[2] = {1.0f - px, px};
    const float wy[2] = {1.0f - py, py};
    const float wz[2] = {1.0f - pz, pz};
    v4f acc = (v4f)(0.0f);
    #pragma unroll
    for (int c = 0; c < 8; ++c) {
        const float w = wx[(c >> 2) & 1] * wy[(c >> 1) & 1] * wz[c & 1];
        acc.x = fmaf(w, e[c].x, acc.x); acc.y = fmaf(w, e[c].y, acc.y);
        acc.z = fmaf(w, e[c].z, acc.z); acc.w = fmaf(w, e[c].w, acc.w);
    }
    __builtin_nontemporal_store(acc, (v4f*)(out + 4 * (size_t)t));
}

extern "C" void kernel_launch(void* const* d_in, const int* in_sizes, int n_in,
                              void* d_out, int out_size, void* d_ws, size_t ws_size,
                              hipStream_t stream) {
    const float* pts = (const float*)d_in[0];
    const int*   p2v = (const int*)d_in[1];
    const float* emb = (const float*)d_in[2];
    const float* cp  = (const float*)d_in[3];
    const int*   c2c = (const int*)d_in[4];
    const float* vox = (const float*)d_in[5];
    float*       out = (float*)d_out;

    const int N  = in_sizes[1];       // 2,000,000 points
    const int NV = in_sizes[4] / 8;   // 500,000 voxels

    // workspace layout (bytes)
    const size_t off_hist  = 0;                        // NV * 4   (2 MB)
    const size_t off_bsums = 2u * 1024u * 1024u;       // <=1024 * 4
    const size_t off_rank  = 4u * 1024u * 1024u;       // N * 4    (8 MB)
    const size_t off_vsort = 12u * 1024u * 1024u;      // N * 4    (8 MB)
    const size_t off_rec   = 20u * 1024u * 1024u;      // N * 16   (32 MB)
    const size_t need = off_rec + (size_t)N * 16u;

    if (ws_size < need) {
        const int block = 256;
        const long long threads = 4LL * N;
        k_direct<<<(int)((threads + block - 1) / block), block, 0, stream>>>(
            pts, p2v, emb, cp, c2c, vox, out, N);
        return;
    }

    unsigned* hist  = (unsigned*)((char*)d_ws + off_hist);
    unsigned* bsums = (unsigned*)((char*)d_ws + off_bsums);
    unsigned* rank  = (unsigned*)((char*)d_ws + off_rank);
    unsigned* vsort = (unsigned*)((char*)d_ws + off_vsort);
    v4f*      rec   = (v4f*)((char*)d_ws + off_rec);

    const int block = 256;
    const int nscan = (NV + 1023) / 1024;   // 489 blocks; k_scan_sums handles <=1024

    k_zero<<<(NV + block - 1) / block, block, 0, stream>>>(hist, NV);
    k_hist_rank<<<(N + block - 1) / block, block, 0, stream>>>(p2v, hist, rank, N);
    k_scan_blocks<<<nscan, 256, 0, stream>>>(hist, bsums, NV);
    k_scan_sums<<<1, 256, 0, stream>>>(bsums, nscan);
    k_add<<<(NV + block - 1) / block, block, 0, stream>>>(hist, bsums, NV);
    k_place<<<(N + block - 1) / block, block, 0, stream>>>(pts, p2v, rank, hist, vsort, rec, N);

    const long long threads = 4LL * N;
    k_main<<<(int)((threads + block - 1) / block), block, 0, stream>>>(
        vsort, rec, emb, cp, c2c, vox, out, N);
}

// Round 4
// 458.525 us; speedup vs baseline: 1.3573x; 1.0425x over previous
//
#include <hip/hip_runtime.h>

// VoxelEncoding via counting-sort by voxel id — single-atomic-pass, ILP-batched.
//   Measured r0-r3: a 1-op/thread returning far-atomic pass runs at ~20 Gop/s
//   = latency(~1000cy) x concurrency(32 waves/CU x 1 outstanding) bound, NOT
//   throughput bound. Fix: 8 points/thread -> 8 independent atomicAdds in
//   flight per wave -> ~8x concurrency. Intra-voxel rank order is arbitrary,
//   so batching preserves correctness (any bijection i->pos with same-voxel
//   adjacency works).
//
//   K0 zero hist -> K1 hist+rank (ONLY atomic pass, 8 pts/thread)
//   -> K2 block scan -> K3 scan block sums
//   -> K5 place (4 pts/thread, float4 pts loads; folds the bsums add, so
//      the old K4 "k_add" 500K-bin RMW pass is deleted):
//      pos = hist[v] + bsums[v>>10] + rank[i]; scatter vsort/rec (no atomics)
//   -> K6 main (unchanged, proven 127us @ FETCH 278MB ~ structural
//      500Kx8x64B emb gather near the random-64B roofline): seq vsort/rec;
//      same-voxel points adjacent -> emb gathers merge in TA/L1; c2c/cp
//      near-sequential; out scattered to orig rows = exactly one full
//      64-B line per point.

typedef float v4f __attribute__((ext_vector_type(4)));

// ---------------- K0: zero histogram ----------------
__global__ void k_zero(unsigned* __restrict__ hist, int n) {
    int i = blockIdx.x * blockDim.x + threadIdx.x;
    if (i < n) hist[i] = 0u;
}

// ---------------- K1: histogram + per-point rank, 8 pts/thread ----------------
__global__ __launch_bounds__(256) void k_hist_rank(const int* __restrict__ p2v,
                                                   unsigned* __restrict__ hist,
                                                   unsigned* __restrict__ rank, int N) {
    const int base = (blockIdx.x * blockDim.x + threadIdx.x) * 8;
    if (base + 7 < N) {
        const int4 a = *(const int4*)(p2v + base);
        const int4 b = *(const int4*)(p2v + base + 4);
        // 8 independent returning atomics in flight (ILP covers far-atomic latency)
        const unsigned r0 = atomicAdd(&hist[a.x], 1u);
        const unsigned r1 = atomicAdd(&hist[a.y], 1u);
        const unsigned r2 = atomicAdd(&hist[a.z], 1u);
        const unsigned r3 = atomicAdd(&hist[a.w], 1u);
        const unsigned r4 = atomicAdd(&hist[b.x], 1u);
        const unsigned r5 = atomicAdd(&hist[b.y], 1u);
        const unsigned r6 = atomicAdd(&hist[b.z], 1u);
        const unsigned r7 = atomicAdd(&hist[b.w], 1u);
        uint4 o0; o0.x = r0; o0.y = r1; o0.z = r2; o0.w = r3;
        uint4 o1; o1.x = r4; o1.y = r5; o1.z = r6; o1.w = r7;
        *(uint4*)(rank + base)     = o0;
        *(uint4*)(rank + base + 4) = o1;
    } else {
        for (int k = 0; k < 8; ++k)
            if (base + k < N) rank[base + k] = atomicAdd(&hist[p2v[base + k]], 1u);
    }
}

// ---------------- K2: per-block exclusive scan (1024 bins/block) ----------------
__global__ __launch_bounds__(256) void k_scan_blocks(unsigned* __restrict__ hist,
                                                     unsigned* __restrict__ bsums, int nbins) {
    __shared__ unsigned tsum[256];
    const int tid = threadIdx.x;
    const int i0 = blockIdx.x * 1024 + tid * 4;
    unsigned v[4]; unsigned s = 0;
    #pragma unroll
    for (int k = 0; k < 4; ++k) {
        unsigned c = (i0 + k < nbins) ? hist[i0 + k] : 0u;
        v[k] = s; s += c;
    }
    tsum[tid] = s; __syncthreads();
    for (int off = 1; off < 256; off <<= 1) {
        unsigned x = tsum[tid];
        unsigned y = (tid >= off) ? tsum[tid - off] : 0u;
        __syncthreads();
        tsum[tid] = x + y;
        __syncthreads();
    }
    unsigned prefix = (tid > 0) ? tsum[tid - 1] : 0u;
    #pragma unroll
    for (int k = 0; k < 4; ++k) {
        if (i0 + k < nbins) hist[i0 + k] = prefix + v[k];
    }
    if (tid == 255) bsums[blockIdx.x] = tsum[255];
}

// ---------------- K3: exclusive scan of block sums (single block, nb <= 1024) ----------------
__global__ __launch_bounds__(256) void k_scan_sums(unsigned* __restrict__ bsums, int nb) {
    __shared__ unsigned tsum[256];
    const int tid = threadIdx.x;
    const int i0 = tid * 4;
    unsigned v[4]; unsigned s = 0;
    #pragma unroll
    for (int k = 0; k < 4; ++k) {
        unsigned c = (i0 + k < nb) ? bsums[i0 + k] : 0u;
        v[k] = s; s += c;
    }
    tsum[tid] = s; __syncthreads();
    for (int off = 1; off < 256; off <<= 1) {
        unsigned x = tsum[tid];
        unsigned y = (tid >= off) ? tsum[tid - off] : 0u;
        __syncthreads();
        tsum[tid] = x + y;
        __syncthreads();
    }
    unsigned prefix = (tid > 0) ? tsum[tid - 1] : 0u;
    #pragma unroll
    for (int k = 0; k < 4; ++k) {
        if (i0 + k < nb) bsums[i0 + k] = prefix + v[k];
    }
}

// ---------------- K5: place payload, 4 pts/thread, NO atomics ----------------
// pos = hist[v] (block-local prefix) + bsums[v>>10] (scanned chunk offsets,
// 2KB L1-hot) + rank[i]  -- folds the old k_add pass into the read.
__global__ __launch_bounds__(256) void k_place(
    const float* __restrict__ pts,
    const int*   __restrict__ p2v,
    const unsigned* __restrict__ rank,
    const unsigned* __restrict__ hist,
    const unsigned* __restrict__ bsums,
    unsigned* __restrict__ vsort,
    v4f*      __restrict__ rec,
    int N)
{
    const int base = (blockIdx.x * blockDim.x + threadIdx.x) * 4;
    if (base + 3 < N) {
        const int4  v4r = *(const int4*)(p2v + base);
        const uint4 r4  = *(const uint4*)(rank + base);
        const v4f* p4 = (const v4f*)pts;
        const size_t f0i = (size_t)(3 * (base >> 2));   // base%4==0 -> 3*base/4
        const v4f f0 = p4[f0i];
        const v4f f1 = p4[f0i + 1];
        const v4f f2 = p4[f0i + 2];

        const unsigned pos0 = hist[v4r.x] + bsums[((unsigned)v4r.x) >> 10] + r4.x;
        const unsigned pos1 = hist[v4r.y] + bsums[((unsigned)v4r.y) >> 10] + r4.y;
        const unsigned pos2 = hist[v4r.z] + bsums[((unsigned)v4r.z) >> 10] + r4.z;
        const unsigned pos3 = hist[v4r.w] + bsums[((unsigned)v4r.w) >> 10] + r4.w;

        vsort[pos0] = (unsigned)v4r.x;
        vsort[pos1] = (unsigned)v4r.y;
        vsort[pos2] = (unsigned)v4r.z;
        vsort[pos3] = (unsigned)v4r.w;

        v4f a;
        a.x = f0.x; a.y = f0.y; a.z = f0.z; a.w = __int_as_float(base + 0);
        rec[pos0] = a;
        a.x = f0.w; a.y = f1.x; a.z = f1.y; a.w = __int_as_float(base + 1);
        rec[pos1] = a;
        a.x = f1.z; a.y = f1.w; a.z = f2.x; a.w = __int_as_float(base + 2);
        rec[pos2] = a;
        a.x = f2.y; a.y = f2.z; a.z = f2.w; a.w = __int_as_float(base + 3);
        rec[pos3] = a;
    } else {
        for (int k = 0; k < 4; ++k) {
            const int i = base + k;
            if (i >= N) break;
            const int v = p2v[i];
            const unsigned pos = hist[v] + bsums[((unsigned)v) >> 10] + rank[i];
            vsort[pos] = (unsigned)v;
            v4f r;
            r.x = pts[3 * (size_t)i + 0];
            r.y = pts[3 * (size_t)i + 1];
            r.z = pts[3 * (size_t)i + 2];
            r.w = __int_as_float(i);
            rec[pos] = r;
        }
    }
}

// ---------------- K6: main interpolation over sorted points ----------------
__global__ __launch_bounds__(256) void k_main(
    const unsigned* __restrict__ vsort, const v4f* __restrict__ rec,
    const float* __restrict__ emb,   // (N_EMB,16)
    const float* __restrict__ cp,    // (N_VOX,3)
    const int*   __restrict__ c2c,   // (N_VOX,8)
    const float* __restrict__ vox,
    float*       __restrict__ out,   // (N,16)
    int N)
{
    const int t = blockIdx.x * blockDim.x + threadIdx.x;
    const int n = t >> 2;        // sorted point index
    const int q = t & 3;         // 4-dim chunk
    if (n >= N) return;

    const unsigned v = vsort[n];
    const v4f r = rec[n];
    const int orig = __float_as_int(r.w);

    const int4* c4 = (const int4*)(c2c + 8 * (size_t)v);
    const int4 ci0 = c4[0];
    const int4 ci1 = c4[1];
    const int cidx[8] = {ci0.x, ci0.y, ci0.z, ci0.w, ci1.x, ci1.y, ci1.z, ci1.w};

    v4f e[8];
    #pragma unroll
    for (int c = 0; c < 8; ++c) {
        e[c] = *(const v4f*)(emb + 16 * (size_t)cidx[c] + 4 * q);
    }

    const float inv_vs = 1.0f / vox[0];
    const float* cpp = cp + 3 * (size_t)v;
    const float px = (r.x - cpp[0]) * inv_vs + 0.5f;
    const float py = (r.y - cpp[1]) * inv_vs + 0.5f;
    const float pz = (r.z - cpp[2]) * inv_vs + 0.5f;
    const float wx[2] = {1.0f - px, px};
    const float wy[2] = {1.0f - py, py};
    const float wz[2] = {1.0f - pz, pz};

    v4f acc = (v4f)(0.0f);
    #pragma unroll
    for (int c = 0; c < 8; ++c) {
        const float w = wx[(c >> 2) & 1] * wy[(c >> 1) & 1] * wz[c & 1];
        acc.x = fmaf(w, e[c].x, acc.x);
        acc.y = fmaf(w, e[c].y, acc.y);
        acc.z = fmaf(w, e[c].z, acc.z);
        acc.w = fmaf(w, e[c].w, acc.w);
    }

    __builtin_nontemporal_store(acc, (v4f*)(out + 16 * (size_t)orig + 4 * q));
}

// ---------------- fallback (no-sort direct), used only if ws too small ----------------
__global__ __launch_bounds__(256) void k_direct(
    const float* __restrict__ pts, const int* __restrict__ p2v,
    const float* __restrict__ emb, const float* __restrict__ cp,
    const int* __restrict__ c2c, const float* __restrict__ vox,
    float* __restrict__ out, int N)
{
    const int t = blockIdx.x * blockDim.x + threadIdx.x;
    const int n = t >> 2, q = t & 3;
    if (n >= N) return;
    const int v = p2v[n];
    const int4* c4 = (const int4*)(c2c + 8 * (size_t)v);
    const int4 ci0 = c4[0], ci1 = c4[1];
    const int cidx[8] = {ci0.x, ci0.y, ci0.z, ci0.w, ci1.x, ci1.y, ci1.z, ci1.w};
    v4f e[8];
    #pragma unroll
    for (int c = 0; c < 8; ++c) e[c] = *(const v4f*)(emb + 16 * (size_t)cidx[c] + 4 * q);
    const float inv_vs = 1.0f / vox[0];
    const float* pp = pts + 3 * (size_t)n;
    const float* cpp = cp + 3 * (size_t)v;
    const float px = (pp[0] - cpp[0]) * inv_vs + 0.5f;
    const float py = (pp[1] - cpp[1]) * inv_vs + 0.5f;
    const float pz = (pp[2] - cpp[2]) * inv_vs + 0.5f;
    const float wx[2] = {1.0f - px, px};
    const float wy[2] = {1.0f - py, py};
    const float wz[2] = {1.0f - pz, pz};
    v4f acc = (v4f)(0.0f);
    #pragma unroll
    for (int c = 0; c < 8; ++c) {
        const float w = wx[(c >> 2) & 1] * wy[(c >> 1) & 1] * wz[c & 1];
        acc.x = fmaf(w, e[c].x, acc.x); acc.y = fmaf(w, e[c].y, acc.y);
        acc.z = fmaf(w, e[c].z, acc.z); acc.w = fmaf(w, e[c].w, acc.w);
    }
    __builtin_nontemporal_store(acc, (v4f*)(out + 4 * (size_t)t));
}

extern "C" void kernel_launch(void* const* d_in, const int* in_sizes, int n_in,
                              void* d_out, int out_size, void* d_ws, size_t ws_size,
                              hipStream_t stream) {
    const float* pts = (const float*)d_in[0];
    const int*   p2v = (const int*)d_in[1];
    const float* emb = (const float*)d_in[2];
    const float* cp  = (const float*)d_in[3];
    const int*   c2c = (const int*)d_in[4];
    const float* vox = (const float*)d_in[5];
    float*       out = (float*)d_out;

    const int N  = in_sizes[1];       // 2,000,000 points
    const int NV = in_sizes[4] / 8;   // 500,000 voxels

    // workspace layout (bytes)
    const size_t off_hist  = 0;                        // NV * 4   (2 MB)
    const size_t off_bsums = 2u * 1024u * 1024u;       // <=1024 * 4
    const size_t off_rank  = 4u * 1024u * 1024u;       // N * 4    (8 MB)
    const size_t off_vsort = 12u * 1024u * 1024u;      // N * 4    (8 MB)
    const size_t off_rec   = 20u * 1024u * 1024u;      // N * 16   (32 MB)
    const size_t need = off_rec + (size_t)N * 16u;

    if (ws_size < need) {
        const int block = 256;
        const long long threads = 4LL * N;
        k_direct<<<(int)((threads + block - 1) / block), block, 0, stream>>>(
            pts, p2v, emb, cp, c2c, vox, out, N);
        return;
    }

    unsigned* hist  = (unsigned*)((char*)d_ws + off_hist);
    unsigned* bsums = (unsigned*)((char*)d_ws + off_bsums);
    unsigned* rank  = (unsigned*)((char*)d_ws + off_rank);
    unsigned* vsort = (unsigned*)((char*)d_ws + off_vsort);
    v4f*      rec   = (v4f*)((char*)d_ws + off_rec);

    const int block = 256;
    const int nscan = (NV + 1023) / 1024;   // 489 blocks; k_scan_sums handles <=1024

    k_zero<<<(NV + block - 1) / block, block, 0, stream>>>(hist, NV);
    k_hist_rank<<<(N + block * 8 - 1) / (block * 8), block, 0, stream>>>(p2v, hist, rank, N);
    k_scan_blocks<<<nscan, 256, 0, stream>>>(hist, bsums, NV);
    k_scan_sums<<<1, 256, 0, stream>>>(bsums, nscan);
    k_place<<<(N + block * 4 - 1) / (block * 4), block, 0, stream>>>(
        pts, p2v, rank, hist, bsums, vsort, rec, N);

    const long long threads = 4LL * N;
    k_main<<<(int)((threads + block - 1) / block), block, 0, stream>>>(
        vsort, rec, emb, cp, c2c, vox, out, N);
}